// Round 2
// baseline (136.439 us; speedup 1.0000x reference)
//
#include <hip/hip_runtime.h>
#include <hip/hip_bf16.h>

#define BATCH 262144
#define NSITES 64

typedef __attribute__((ext_vector_type(8))) short short8;
typedef __attribute__((ext_vector_type(4))) float f32x4;

__device__ __forceinline__ unsigned cvt_pk_bf16(float lo, float hi) {
  unsigned r;
  asm("v_cvt_pk_bf16_f32 %0, %1, %2" : "=v"(r) : "v"(lo), "v"(hi));
  return r;
}

// slot k = [k4 k3 | k2 k1 k0] -> logical chi = 16*k2 + 4*(k4k3) + (k1k0)
__device__ __forceinline__ int qmap(int k) {
  return (((k >> 2) & 1) << 4) | (((k >> 3) & 3) << 2) | (k & 3);
}
// inverse: chi -> slot
__device__ __forceinline__ int qinv(int chi) {
  return (((chi >> 2) & 3) << 3) | (((chi >> 4) & 1) << 2) | (chi & 3);
}

// ---- pre-kernel: pack Ep[s][m][c][k] = bf16( cores[s][b][m][c] - (b==c) ),
//      k = qinv(b). Layout row-major, row = 32 bf16 = 64B. Total 63*2*32*32*2B = 258KB.
__global__ void pack_E(const float* __restrict__ cores, unsigned short* __restrict__ Ep) {
  int idx = blockIdx.x * 256 + threadIdx.x;
  if (idx >= (NSITES - 1) * 2048) return;
  int s = idx >> 11;
  int r = idx & 2047;
  int b = r >> 6;        // cores[s][b][m][c]
  int m = (r >> 5) & 1;
  int c = r & 31;
  float f = cores[idx] - ((b == c) ? 1.0f : 0.0f);
  __hip_bfloat16 h = __float2bfloat16(f);
  Ep[((s * 2 + m) * 32 + c) * 32 + qinv(b)] = *(unsigned short*)&h;
}

__global__ __launch_bounds__(256, 4) void mps_chain_kernel(
    const float* __restrict__ X, const float* __restrict__ core0,
    const float* __restrict__ coreN, const unsigned short* __restrict__ Ep,
    float* __restrict__ out) {
  const int tid = threadIdx.x;
  const int lane = tid & 63;
  const int wave = tid >> 6;
  const int col = lane & 15;  // batch column within 16-wide tile
  const int g = lane >> 4;    // k-group (slots 8g..8g+7)
  const int abase = blockIdx.x * 256 + wave * 64;

  // ---- v0 = X[0] @ core0, in permuted slot order (scalar L2 loads, once) ----
  float c0[2][8];
#pragma unroll
  for (int m = 0; m < 2; ++m)
#pragma unroll
    for (int t = 0; t < 8; ++t) c0[m][t] = core0[m * 32 + qmap(8 * g + t)];

  float v[4][8];
#pragma unroll
  for (int j = 0; j < 4; ++j) {
    const float2 xj = *(const float2*)(X + 2 * (size_t)(abase + j * 16 + col));
#pragma unroll
    for (int t = 0; t < 8; ++t) v[j][t] = xj.x * c0[0][t] + xj.y * c0[1][t];
  }

  // ---- prefetch pipeline ----
  // A fragments for step s (Ac), step s+1 (An); X for step s (xc), s+1 (xm), s+2 (xn)
  const short8* EpV = (const short8*)Ep;  // 16B granules; row of 32 bf16 = 4 granules
  // fragment index for (s, m, rowhalf): ((s*2+m)*32 + row)*32 + 8g  bytes*2 /16 ...
  // granule index = (((s*2+m)*32 + row) * 32 + 8*g) / 8 = ((s*2+m)*32 + row)*4 + g
  const int rA = col, rB = col + 16;
#define FRAG(s, m, row) EpV[(((s)*2 + (m)) * 32 + (row)) * 4 + g]

  short8 Ac0 = FRAG(0, 0, rA), Ac1 = FRAG(0, 0, rB);
  short8 Ac2 = FRAG(0, 1, rA), Ac3 = FRAG(0, 1, rB);

  float2 xc[4], xm[4];
#pragma unroll
  for (int j = 0; j < 4; ++j) {
    xc[j] = *(const float2*)(X + 2 * ((size_t)1 * BATCH + abase + j * 16 + col));
    xm[j] = *(const float2*)(X + 2 * ((size_t)2 * BATCH + abase + j * 16 + col));
  }

  // ---- main chain: v <- (x0+x1)*v + x0*(v@E0) + x1*(v@E1) ----
#pragma unroll 1
  for (int s = 1; s < NSITES; ++s) {
    // prefetch E for step s+1 (pack index s, clamped)
    const int sn = (s < NSITES - 1) ? s : NSITES - 2;
    short8 An0 = FRAG(sn, 0, rA), An1 = FRAG(sn, 0, rB);
    short8 An2 = FRAG(sn, 1, rA), An3 = FRAG(sn, 1, rB);
    // prefetch X for step s+2 (clamped)
    const size_t sx = (s + 2 < NSITES) ? (size_t)(s + 2) : (size_t)(NSITES - 1);
    float2 xn[4];
#pragma unroll
    for (int j = 0; j < 4; ++j)
      xn[j] = *(const float2*)(X + 2 * (sx * BATCH + abase + j * 16 + col));

#pragma unroll
    for (int j = 0; j < 4; ++j) {
      union {
        short8 s8;
        unsigned u[4];
      } vb;
      vb.u[0] = cvt_pk_bf16(v[j][0], v[j][1]);
      vb.u[1] = cvt_pk_bf16(v[j][2], v[j][3]);
      vb.u[2] = cvt_pk_bf16(v[j][4], v[j][5]);
      vb.u[3] = cvt_pk_bf16(v[j][6], v[j][7]);
      const f32x4 z = {0.f, 0.f, 0.f, 0.f};
      f32x4 r0lo = __builtin_amdgcn_mfma_f32_16x16x32_bf16(Ac0, vb.s8, z, 0, 0, 0);
      f32x4 r0hi = __builtin_amdgcn_mfma_f32_16x16x32_bf16(Ac1, vb.s8, z, 0, 0, 0);
      f32x4 r1lo = __builtin_amdgcn_mfma_f32_16x16x32_bf16(Ac2, vb.s8, z, 0, 0, 0);
      f32x4 r1hi = __builtin_amdgcn_mfma_f32_16x16x32_bf16(Ac3, vb.s8, z, 0, 0, 0);
      const float x0 = xc[j].x, x1 = xc[j].y;
      const float s01 = x0 + x1;
#pragma unroll
      for (int t = 0; t < 4; ++t) {
        v[j][t] = s01 * v[j][t] + x0 * r0lo[t] + x1 * r1lo[t];
        v[j][4 + t] = s01 * v[j][4 + t] + x0 * r0hi[t] + x1 * r1hi[t];
      }
    }

    // rotate pipeline
    Ac0 = An0; Ac1 = An1; Ac2 = An2; Ac3 = An3;
#pragma unroll
    for (int j = 0; j < 4; ++j) { xc[j] = xm[j]; xm[j] = xn[j]; }
  }
#undef FRAG

  // ---- epilogue: out = |v @ coreN| ----
  float cN[8][2];
#pragma unroll
  for (int t = 0; t < 8; ++t) {
    cN[t][0] = coreN[qmap(8 * g + t) * 2 + 0];
    cN[t][1] = coreN[qmap(8 * g + t) * 2 + 1];
  }
#pragma unroll
  for (int j = 0; j < 4; ++j) {
    float p0 = 0.f, p1 = 0.f;
#pragma unroll
    for (int t = 0; t < 8; ++t) {
      p0 += v[j][t] * cN[t][0];
      p1 += v[j][t] * cN[t][1];
    }
    p0 += __shfl_xor(p0, 16);
    p0 += __shfl_xor(p0, 32);
    p1 += __shfl_xor(p1, 16);
    p1 += __shfl_xor(p1, 32);
    if (g == 0) {
      const int a = abase + j * 16 + col;
      out[2 * a] = fabsf(p0);
      out[2 * a + 1] = fabsf(p1);
    }
  }
}

extern "C" void kernel_launch(void* const* d_in, const int* in_sizes, int n_in,
                              void* d_out, int out_size, void* d_ws, size_t ws_size,
                              hipStream_t stream) {
  const float* X = (const float*)d_in[0];
  const float* core0 = (const float*)d_in[1];
  const float* cores = (const float*)d_in[2];
  const float* coreN = (const float*)d_in[3];
  float* out = (float*)d_out;
  unsigned short* Ep = (unsigned short*)d_ws;  // 258048 bytes

  hipLaunchKernelGGL(pack_E, dim3(((NSITES - 1) * 2048 + 255) / 256), dim3(256), 0, stream,
                     cores, Ep);
  hipLaunchKernelGGL(mps_chain_kernel, dim3(BATCH / 256), dim3(256), 0, stream, X, core0,
                     coreN, Ep, out);
}

// Round 5
// 106.980 us; speedup vs baseline: 1.2754x; 1.2754x over previous
//
#include <hip/hip_runtime.h>
#include <hip/hip_bf16.h>

#define BATCH 262144
#define NSITES 64

typedef __attribute__((ext_vector_type(8))) short short8;
typedef __attribute__((ext_vector_type(4))) float f32x4;

__device__ __forceinline__ unsigned cvt_pk_bf16(float a, float b) {
  unsigned r;
  asm("v_cvt_pk_bf16_f32 %0, %1, %2" : "=v"(r) : "v"(a), "v"(b));
  return r;
}

// slot k = [k4 k3 | k2 k1 k0] -> logical chi = 16*k2 + 4*(k4k3) + (k1k0)
__device__ __forceinline__ int qmap(int k) {
  return (((k >> 2) & 1) << 4) | (((k >> 3) & 3) << 2) | (k & 3);
}

// pack: element idx = ((p*4 + f)*64 + l)*8 + t   (chunk = 16B = 8 bf16)
// f = m*2 + h ; l = g*16 + col ; value = bf16(cores[p][qmap(8g+t)][m][h*16+col] - delta)
// i.e. chunk (p,f,l) is the MFMA A-fragment for lane l, matrix m, row-half h of step p+1.
__global__ void pack_E(const float* __restrict__ cores, unsigned short* __restrict__ Ep) {
  int idx = blockIdx.x * 256 + threadIdx.x;
  if (idx >= (NSITES - 1) * 2048) return;
  int t = idx & 7;
  int l = (idx >> 3) & 63;
  int f = (idx >> 9) & 3;
  int p = idx >> 11;
  int g = l >> 4, col = l & 15;
  int m = f >> 1, h = f & 1;
  int k = 8 * g + t, c = h * 16 + col;
  int b = qmap(k);
  float val = cores[((p * 32 + b) * 2 + m) * 32 + c] - ((b == c) ? 1.0f : 0.0f);
  __hip_bfloat16 hv = __float2bfloat16(val);
  Ep[idx] = *(unsigned short*)&hv;
}

__device__ __forceinline__ void gll16(const void* g, void* l) {
  __builtin_amdgcn_global_load_lds(
      (const __attribute__((address_space(1))) unsigned*)g,
      (__attribute__((address_space(3))) unsigned*)l, 16, 0, 0);
}

#define BODYJ(jj, xx0, xx1)                                                     \
  {                                                                             \
    union { short8 s8; unsigned u[4]; } vb;                                     \
    vb.u[0] = cvt_pk_bf16(v[jj][0], v[jj][1]);                                  \
    vb.u[1] = cvt_pk_bf16(v[jj][2], v[jj][3]);                                  \
    vb.u[2] = cvt_pk_bf16(v[jj][4], v[jj][5]);                                  \
    vb.u[3] = cvt_pk_bf16(v[jj][6], v[jj][7]);                                  \
    const f32x4 z = {0.f, 0.f, 0.f, 0.f};                                       \
    f32x4 r0lo = __builtin_amdgcn_mfma_f32_16x16x32_bf16(A0, vb.s8, z, 0, 0, 0); \
    f32x4 r0hi = __builtin_amdgcn_mfma_f32_16x16x32_bf16(A1, vb.s8, z, 0, 0, 0); \
    f32x4 r1lo = __builtin_amdgcn_mfma_f32_16x16x32_bf16(A2, vb.s8, z, 0, 0, 0); \
    f32x4 r1hi = __builtin_amdgcn_mfma_f32_16x16x32_bf16(A3, vb.s8, z, 0, 0, 0); \
    const float ss = (xx0) + (xx1);                                             \
    _Pragma("unroll") for (int t = 0; t < 4; ++t) {                             \
      v[jj][t] = ss * v[jj][t] + (xx0)*r0lo[t] + (xx1)*r1lo[t];                 \
      v[jj][4 + t] = ss * v[jj][4 + t] + (xx0)*r0hi[t] + (xx1)*r1hi[t];         \
    }                                                                           \
  }

__global__ __launch_bounds__(256, 4) void mps_chain_kernel(
    const float* __restrict__ X, const float* __restrict__ core0,
    const float* __restrict__ coreN, const unsigned short* __restrict__ Ep,
    float* __restrict__ out) {
  __shared__ __align__(16) char Elds[2][4096];
  const int tid = threadIdx.x;
  const int lane = tid & 63;
  const int wave = tid >> 6;
  const int col = lane & 15;  // batch column within 16-wide tile
  const int g = lane >> 4;    // k-group (slots 8g..8g+7)
  const int abase = blockIdx.x * 256 + wave * 64;
  const char* Epc = (const char*)Ep;

  // ---- prologue: stage E(1) into buf0 (async DMA), compute v0 meanwhile ----
  gll16(Epc + (size_t)tid * 16, &Elds[0][wave * 1024]);

  float c0[2][8];
#pragma unroll
  for (int m = 0; m < 2; ++m)
#pragma unroll
    for (int t = 0; t < 8; ++t) c0[m][t] = core0[m * 32 + qmap(8 * g + t)];

  float v[4][8];
#pragma unroll
  for (int jj = 0; jj < 4; ++jj) {
    const float2 xj = *(const float2*)(X + 2 * (size_t)(abase + jj * 16 + col));
#pragma unroll
    for (int t = 0; t < 8; ++t) v[jj][t] = xj.x * c0[0][t] + xj.y * c0[1][t];
  }

  // X for step 1
  float xl[4], xh[4];
#pragma unroll
  for (int jj = 0; jj < 4; ++jj) {
    const float2 t_ =
        *(const float2*)(X + 2 * ((size_t)1 * BATCH + abase + jj * 16 + col));
    xl[jj] = t_.x;
    xh[jj] = t_.y;
  }
  __syncthreads();  // drains the E(1) DMA

  // ---- main chain: one barrier per step; everything issued in step s
  //      completes by the (mandatory) vmcnt(0) drain at its barrier ----
#pragma unroll 1
  for (int s = 1; s < NSITES; ++s) {
    const int buf = (s - 1) & 1;
    if (s < NSITES - 1)  // prefetch E(s+1) panel into the other buffer
      gll16(Epc + (size_t)s * 4096 + (size_t)tid * 16, &Elds[buf ^ 1][wave * 1024]);

    // prefetch X(s+1)
    const size_t sx = (s + 1 < NSITES) ? (size_t)(s + 1) : (size_t)(NSITES - 1);
    float2 xn[4];
#pragma unroll
    for (int jj = 0; jj < 4; ++jj)
      xn[jj] = *(const float2*)(X + 2 * (sx * BATCH + abase + jj * 16 + col));

    // A fragments for this step (clean lane-linear ds_read_b128)
    const short8* ep = (const short8*)&Elds[buf][lane * 16];
    const short8 A0 = ep[0], A1 = ep[64], A2 = ep[128], A3 = ep[192];

    BODYJ(0, xl[0], xh[0]);
    BODYJ(1, xl[1], xh[1]);
    BODYJ(2, xl[2], xh[2]);
    BODYJ(3, xl[3], xh[3]);

#pragma unroll
    for (int jj = 0; jj < 4; ++jj) {
      xl[jj] = xn[jj].x;
      xh[jj] = xn[jj].y;
    }
    __syncthreads();
  }

  // ---- epilogue: out = |v @ coreN| ----
  float cN[8][2];
#pragma unroll
  for (int t = 0; t < 8; ++t) {
    cN[t][0] = coreN[qmap(8 * g + t) * 2 + 0];
    cN[t][1] = coreN[qmap(8 * g + t) * 2 + 1];
  }
#pragma unroll
  for (int jj = 0; jj < 4; ++jj) {
    float p0 = 0.f, p1 = 0.f;
#pragma unroll
    for (int t = 0; t < 8; ++t) {
      p0 += v[jj][t] * cN[t][0];
      p1 += v[jj][t] * cN[t][1];
    }
    p0 += __shfl_xor(p0, 16);
    p0 += __shfl_xor(p0, 32);
    p1 += __shfl_xor(p1, 16);
    p1 += __shfl_xor(p1, 32);
    if (g == 0) {
      const int a = abase + jj * 16 + col;
      out[2 * a] = fabsf(p0);
      out[2 * a + 1] = fabsf(p1);
    }
  }
}

extern "C" void kernel_launch(void* const* d_in, const int* in_sizes, int n_in,
                              void* d_out, int out_size, void* d_ws, size_t ws_size,
                              hipStream_t stream) {
  const float* X = (const float*)d_in[0];
  const float* core0 = (const float*)d_in[1];
  const float* cores = (const float*)d_in[2];
  const float* coreN = (const float*)d_in[3];
  float* out = (float*)d_out;
  unsigned short* Ep = (unsigned short*)d_ws;  // 258048 bytes

  hipLaunchKernelGGL(pack_E, dim3(((NSITES - 1) * 2048 + 255) / 256), dim3(256), 0, stream,
                     cores, Ep);
  hipLaunchKernelGGL(mps_chain_kernel, dim3(BATCH / 256), dim3(256), 0, stream, X, core0,
                     coreN, Ep, out);
}